// Round 6
// baseline (71769.470 us; speedup 1.0000x reference)
//
#include <hip/hip_runtime.h>

#define TT    8192
#define HD    1024
#define NCB   64        // compute blocks (block 1..64); block 0 = sequencer
#define NTHR  1024
#define NBUF  4         // h ring depth — see race-freedom proof below
#define NREP  8         // flag replicas, one 64B line each

typedef int i32x2 __attribute__((ext_vector_type(2)));

// ---- LLC-coherent accesses (sc0 sc1 = bypass L1+L2, coherent at MALL) ----
__device__ __forceinline__ unsigned llc_load1(const unsigned* p) {
  unsigned r;
  asm volatile("global_load_dword %0, %1, off sc0 sc1\n\ts_waitcnt vmcnt(0)"
               : "=v"(r) : "v"(p) : "memory");
  return r;
}
__device__ __forceinline__ void llc_load_pair8(const unsigned* p,
                                               unsigned& v, unsigned& tg) {
  i32x2 r;
  asm volatile("global_load_dwordx2 %0, %1, off sc0 sc1\n\ts_waitcnt vmcnt(0)"
               : "=v"(r) : "v"(p) : "memory");
  v = (unsigned)r.x; tg = (unsigned)r.y;
}
__device__ __forceinline__ void llc_store2(unsigned* p, unsigned lo, unsigned hi) {
  i32x2 v; v.x = (int)lo; v.y = (int)hi;
  asm volatile("global_store_dwordx2 %0, %1, off sc0 sc1"
               :: "v"(p), "v"(v) : "memory");
}
__device__ __forceinline__ void llc_store1(unsigned* p, unsigned v) {
  asm volatile("global_store_dword %0, %1, off sc0 sc1"
               :: "v"(p), "v"(v) : "memory");
}

__device__ __forceinline__ float sigf(float z) {
  return 1.0f / (1.0f + __expf(-z));
}
__device__ __forceinline__ float tanh_fast(float z) {
  float az = fabsf(z);
  float e  = __expf(2.0f * az);          // >= 1
  float t  = 1.0f - 2.0f / (e + 1.0f);
  return z < 0.0f ? -t : t;
}

#define FMA4(acc, hvv, wvv)                                      \
  acc = fmaf((hvv).x, (wvv).x, acc);                             \
  acc = fmaf((hvv).y, (wvv).y, acc);                             \
  acc = fmaf((hvv).z, (wvv).z, acc);                             \
  acc = fmaf((hvv).w, (wvv).w, acc);

// hbuf: unsigned[NBUF][HD][2] {value_bits, tag}; h of step t -> ring t%4,
// tag t+1.  flag[r*16]: replica flag words; flag >= t  <=>  all step-(t-1)
// h-pairs verified at MALL by the sequencer.
//
// RACE-FREEDOM (4-deep ring): buffer (t-1)%4 is next overwritten by
// producers of step t+3, which requires flag >= t+3, which the sequencer
// raises only after ALL step-(t+2) stores, which requires every block
// finished step t+2, which requires it READ step-(t+1) data, which (by the
// same chain one step back) requires every block read step-t data from
// buffer (t-1)%4.  So no producer can overwrite a buffer any consumer has
// yet to read.  (2-deep ring lacks this chain — latent deadlock in R3/R5.)
extern "C" __global__ __launch_bounds__(NTHR, 1)
void lstm_persistent(const float* __restrict__ x,
                     const float* __restrict__ W_ih,
                     const float* __restrict__ W_hh,
                     const float* __restrict__ b_ih,
                     const float* __restrict__ b_hh,
                     const float* __restrict__ W_fc,
                     const float* __restrict__ b_fc,
                     float* __restrict__ out,
                     unsigned* __restrict__ flag,
                     unsigned* __restrict__ hbuf)
{
  __shared__ float x_lds[TT];     // 32 KB: whole input sequence
  __shared__ float h_lds[HD];     //  4 KB: broadcast of h_{t-1}

  const int tid  = threadIdx.x;
  const int blk  = blockIdx.x;

  // ================= block 0: dedicated sequencer ========================
  if (blk == 0) {
    // thread tid owns the tag word of unit tid's pair
    for (int t = 0; t < TT; ++t) {
      const unsigned* tagp = hbuf + (((t & (NBUF - 1)) * HD + tid) * 2 + 1);
      while (llc_load1(tagp) < (unsigned)(t + 1)) { }
      __syncthreads();                      // all 1024 tags verified
      if (tid < NREP)
        llc_store1(flag + (tid << 4), (unsigned)(t + 1));
    }
    return;
  }

  // ================= blocks 1..64: compute ===============================
  const int cb   = blk - 1;       // 0..63
  const int wave = tid >> 6;      // 0..15 — this wave's unit offset
  const int lane = tid & 63;
  const int g    = lane >> 4;     // gate 0..3 (i,f,g,o)
  const int kc   = lane & 15;     // k-chunk within the 1024-dot
  const int unit = cb * 16 + wave;

  // ---- one-time staging -------------------------------------------------
  for (int i = tid; i < TT / 4; i += NTHR)
    ((float4*)x_lds)[i] = ((const float4*)x)[i];

  // W_hh row (gate g, unit) — lane covers k = m*64 + kc*4 + {0..3}
  float4 w4[16];
  {
    const float* wr = W_hh + (size_t)(g * HD + unit) * HD + kc * 4;
#pragma unroll
    for (int m = 0; m < 16; ++m)
      w4[m] = *((const float4*)(wr + m * 64));
  }
  float4 wfc4[4];
#pragma unroll
  for (int m = 0; m < 4; ++m)
    wfc4[m] = *((const float4*)(W_fc + m * 256 + lane * 4));
  const float bfc_val = b_fc[0];

  float wih_g[4], bs_g[4];
#pragma unroll
  for (int q = 0; q < 4; ++q) {
    int r = q * HD + unit;
    wih_g[q] = W_ih[r];
    bs_g[q]  = b_ih[r] + b_hh[r];
  }
  float c_state = 0.0f;
  __syncthreads();                // x_lds ready

  const unsigned* flag_mine = flag + ((cb & (NREP - 1)) << 4);

  // ---- the sequential scan ---------------------------------------------
  for (int t = 0; t < TT; ++t) {
    const bool doproj = (t > 0) && (wave == 1) && (cb == (t & 63));
    float accs = 0.0f;
    float4 hp4[4];

    if (t > 0) {
      // 1) cheap gate: replica flag (1 coalesced tx per wave per round)
      while (llc_load1(flag_mine) < (unsigned)t) { }
      // 2) one verified 8-B pair per thread (hot in MALL, exits in 1 iter)
      const unsigned* src = hbuf + (((t - 1) & (NBUF - 1)) * HD + tid) * 2;
      unsigned v, tg;
      do {
        llc_load_pair8(src, v, tg);
      } while (tg != (unsigned)t);
      h_lds[tid] = __uint_as_float(v);
      __syncthreads();

      // fragments + 64 FMAs (4 independent sub-chains)
      const float* hp = h_lds + kc * 4;
      float s0 = 0.f, s1 = 0.f, s2 = 0.f, s3 = 0.f;
#pragma unroll
      for (int mb = 0; mb < 4; ++mb) {
        float4 ha = *((const float4*)(hp + (mb * 4 + 0) * 64));
        float4 hb = *((const float4*)(hp + (mb * 4 + 1) * 64));
        float4 hc = *((const float4*)(hp + (mb * 4 + 2) * 64));
        float4 hd = *((const float4*)(hp + (mb * 4 + 3) * 64));
        FMA4(s0, ha, w4[mb * 4 + 0]);
        FMA4(s1, hb, w4[mb * 4 + 1]);
        FMA4(s2, hc, w4[mb * 4 + 2]);
        FMA4(s3, hd, w4[mb * 4 + 3]);
      }
      accs = (s0 + s1) + (s2 + s3);

      if (doproj) {
#pragma unroll
        for (int m = 0; m < 4; ++m)
          hp4[m] = *((const float4*)(h_lds + m * 256 + lane * 4));
      }
    }

    // 4-round butterfly over kc: every lane in a gate-group gets the row sum
#pragma unroll
    for (int s = 1; s < 16; s <<= 1)
      accs += __shfl_xor(accs, s);

    float gi = __shfl(accs, 0);
    float gf = __shfl(accs, 16);
    float gg = __shfl(accs, 32);
    float go = __shfl(accs, 48);

    if (lane == 0) {
      float xt = x_lds[t];
      gi += fmaf(xt, wih_g[0], bs_g[0]);
      gf += fmaf(xt, wih_g[1], bs_g[1]);
      gg += fmaf(xt, wih_g[2], bs_g[2]);
      go += fmaf(xt, wih_g[3], bs_g[3]);
      c_state  = sigf(gf) * c_state + sigf(gi) * tanh_fast(gg);
      float hn = sigf(go) * tanh_fast(c_state);
      llc_store2(hbuf + (((t & (NBUF - 1)) * HD + unit) * 2),
                 __float_as_uint(hn), (unsigned)(t + 1));  // fire & forget
    }

    // fused output projection for step t-1 (register-only, off crit path)
    if (doproj) {
      float p = 0.f;
#pragma unroll
      for (int m = 0; m < 4; ++m) { FMA4(p, hp4[m], wfc4[m]); }
#pragma unroll
      for (int s = 1; s < 64; s <<= 1) p += __shfl_xor(p, s);
      if (lane == 0) out[t - 1] = p + bfc_val;
    }
  }

  // ---- epilogue: out[TT-1] by compute block 0 (blk 1) -------------------
  if (cb == 0) {
    const unsigned* src = hbuf + (((TT - 1) & (NBUF - 1)) * HD + tid) * 2;
    unsigned v, tg;
    do {
      llc_load_pair8(src, v, tg);
    } while (tg != (unsigned)TT);
    h_lds[tid] = __uint_as_float(v);
    __syncthreads();
    if (wave == 1) {
      float p = 0.f;
#pragma unroll
      for (int m = 0; m < 4; ++m) {
        float4 hm = *((const float4*)(h_lds + m * 256 + lane * 4));
        FMA4(p, hm, wfc4[m]);
      }
#pragma unroll
      for (int s = 1; s < 64; s <<= 1) p += __shfl_xor(p, s);
      if (lane == 0) out[TT - 1] = p + bfc_val;
    }
  }
}

extern "C" void kernel_launch(void* const* d_in, const int* in_sizes, int n_in,
                              void* d_out, int out_size, void* d_ws, size_t ws_size,
                              hipStream_t stream) {
  const float* x   = (const float*)d_in[0];
  const float* Wih = (const float*)d_in[1];
  const float* Whh = (const float*)d_in[2];
  const float* bih = (const float*)d_in[3];
  const float* bhh = (const float*)d_in[4];
  const float* Wfc = (const float*)d_in[5];
  const float* bfc = (const float*)d_in[6];
  float* out = (float*)d_out;

  // ws layout: [flag: NREP lines of 64 B][hbuf: NBUF*HD tagged pairs = 32 KB]
  unsigned* flag = (unsigned*)d_ws;
  unsigned* hbuf = flag + NREP * 16;
  size_t init_bytes = (NREP * 16 + NBUF * HD * 2) * sizeof(unsigned);

  // zeros: tag 0 never equals any expected tag (>=1); flag 0 < any t
  hipMemsetAsync(d_ws, 0, init_bytes, stream);
  hipLaunchKernelGGL(lstm_persistent, dim3(NCB + 1), dim3(NTHR), 0, stream,
                     x, Wih, Whh, bih, bhh, Wfc, bfc, out, flag, hbuf);
}

// Round 7
// 42640.927 us; speedup vs baseline: 1.6831x; 1.6831x over previous
//
#include <hip/hip_runtime.h>

#define TT    8192
#define HD    1024
#define NCB   64        // compute blocks; block cb owns units cb*16..cb*16+15
#define NTHR  256
#define NBUF  4         // h ring depth — overwrite-safety proof below

typedef float f32x4 __attribute__((ext_vector_type(4)));

// ---- LLC-coherent accesses (sc0 sc1 = bypass L1+L2, coherent at MALL) ----
__device__ __forceinline__ unsigned llc_load1(const unsigned* p) {
  unsigned r;
  asm volatile("global_load_dword %0, %1, off sc0 sc1\n\ts_waitcnt vmcnt(0)"
               : "=v"(r) : "v"(p) : "memory");
  return r;
}
__device__ __forceinline__ f32x4 llc_load4f(const float* p) {
  f32x4 r;
  asm volatile("global_load_dwordx4 %0, %1, off sc0 sc1\n\ts_waitcnt vmcnt(0)"
               : "=v"(r) : "v"(p) : "memory");
  return r;
}
__device__ __forceinline__ void llc_store1f(float* p, float v) {
  asm volatile("global_store_dword %0, %1, off sc0 sc1" :: "v"(p), "v"(v) : "memory");
}
__device__ __forceinline__ void llc_store1u(unsigned* p, unsigned v) {
  asm volatile("global_store_dword %0, %1, off sc0 sc1" :: "v"(p), "v"(v) : "memory");
}
__device__ __forceinline__ void vm_drain() {
  asm volatile("s_waitcnt vmcnt(0)" ::: "memory");
}

__device__ __forceinline__ float sigf(float z) {
  return 1.0f / (1.0f + __expf(-z));
}
__device__ __forceinline__ float tanh_fast(float z) {
  float az = fabsf(z);
  float e  = __expf(2.0f * az);          // >= 1
  float t  = 1.0f - 2.0f / (e + 1.0f);
  return z < 0.0f ? -t : t;
}

#define FMA4(acc, hvv, wvv)                                      \
  acc = fmaf((hvv).x, (wvv).x, acc);                             \
  acc = fmaf((hvv).y, (wvv).y, acc);                             \
  acc = fmaf((hvv).z, (wvv).z, acc);                             \
  acc = fmaf((hvv).w, (wvv).w, acc);

// vbuf: float[NBUF][HD] h ring (values only).  done: unsigned[NCB];
// done[cb] = t+1  <=>  block cb's 16 h-values for step t are ACKED at the
// MALL (per-wave vmcnt(0) drain + block barrier precede the done-store).
// Consumers gate on all 64 done words >= t — no tags, no verify loops.
//
// RING SAFETY (NBUF=4): producer of step t+3 overwrites buffer (t-1)%4 only
// after passing gate done>=t+3 => all blocks stored h_{t+2} => each block
// finished step t+2 => it read h_{t+1} => it passed gate done>=t+1 => ...
// => every block's read of h_t (from buffer (t-1)%4) completed.  QED.
extern "C" __global__ __launch_bounds__(NTHR, 1)
void lstm_persistent(const float* __restrict__ x,
                     const float* __restrict__ W_ih,
                     const float* __restrict__ W_hh,
                     const float* __restrict__ b_ih,
                     const float* __restrict__ b_hh,
                     const float* __restrict__ W_fc,
                     const float* __restrict__ b_fc,
                     float* __restrict__ out,
                     unsigned* __restrict__ done,
                     float* __restrict__ vbuf)
{
  __shared__ float x_lds[TT];     // 32 KB: whole input sequence
  __shared__ float h_lds[HD];     //  4 KB: broadcast of h_{t-1}

  const int tid   = threadIdx.x;
  const int wave  = tid >> 6;     // 0..3
  const int lane  = tid & 63;
  const int g     = lane >> 4;    // gate 0..3 (i,f,g,o)
  const int kc    = lane & 15;    // k-chunk within the 1024-dot
  const int cb    = blockIdx.x;   // 0..63
  const int ubase = cb * 16 + wave * 4;   // this wave's 4 hidden units

  // ---- one-time staging -------------------------------------------------
  for (int i = tid; i < TT / 4; i += NTHR)
    ((float4*)x_lds)[i] = ((const float4*)x)[i];

  // W_hh rows for 4 units x this lane's gate g. Lane covers
  // k = m*64 + kc*4 + {0..3}, m=0..15.  4*16 float4 = 256 VGPRs.
  float4 w4[4][16];
#pragma unroll
  for (int j = 0; j < 4; ++j) {
    const float* wr = W_hh + (size_t)(g * HD + ubase + j) * HD + kc * 4;
#pragma unroll
    for (int m = 0; m < 16; ++m)
      w4[j][m] = *((const float4*)(wr + m * 64));
  }
  float4 wfc4[4];
#pragma unroll
  for (int m = 0; m < 4; ++m)
    wfc4[m] = *((const float4*)(W_fc + m * 256 + lane * 4));
  const float bfc_val = b_fc[0];

  // lanes 0..3 own units ubase+lane: their gate coefficients
  float wih_g[4], bs_g[4];
  {
    const int ul = ubase + (lane & 3);
#pragma unroll
    for (int q = 0; q < 4; ++q) {
      int r = q * HD + ul;
      wih_g[q] = W_ih[r];
      bs_g[q]  = b_ih[r] + b_hh[r];
    }
  }
  float c_state = 0.0f;
  __syncthreads();                // x_lds ready

  // ---- the sequential scan ---------------------------------------------
  for (int t = 0; t < TT; ++t) {
    const bool doproj = (t > 0) && (wave == 1) && (cb == (t & 63));
    float acc0 = 0.f, acc1 = 0.f, acc2 = 0.f, acc3 = 0.f;
    float4 hp4[4];

    if (t > 0) {
      // gate: lane L polls done[L]; one 4-line coalesced read per round
      for (;;) {
        unsigned v = llc_load1(done + lane);
        if (__all((int)v >= t)) break;
      }
      // certified values: one float4 per thread (4 KB per block total)
      f32x4 hv = llc_load4f(vbuf + ((t - 1) & (NBUF - 1)) * HD + tid * 4);
      ((f32x4*)h_lds)[tid] = hv;
      __syncthreads();

      // 4 units x 64 FMAs, h fragment reused across units
      const float* hp = h_lds + kc * 4;
#pragma unroll
      for (int m = 0; m < 16; ++m) {
        float4 hm = *((const float4*)(hp + m * 64));
        FMA4(acc0, hm, w4[0][m]);
        FMA4(acc1, hm, w4[1][m]);
        FMA4(acc2, hm, w4[2][m]);
        FMA4(acc3, hm, w4[3][m]);
      }

      if (doproj) {
#pragma unroll
        for (int m = 0; m < 4; ++m)
          hp4[m] = *((const float4*)(h_lds + m * 256 + lane * 4));
      }
    }

    // butterfly within each 16-lane gate-group (4 rounds, 4 accs)
#pragma unroll
    for (int s = 1; s < 16; s <<= 1) {
      acc0 += __shfl_xor(acc0, s);
      acc1 += __shfl_xor(acc1, s);
      acc2 += __shfl_xor(acc2, s);
      acc3 += __shfl_xor(acc3, s);
    }
    // gather: lane j (j<4) collects unit j's 4 gate sums from lanes 0/16/32/48
    float gi = 0.f, gf = 0.f, gg = 0.f, go = 0.f;
#pragma unroll
    for (int j = 0; j < 4; ++j) {
      float a  = (j == 0) ? acc0 : (j == 1) ? acc1 : (j == 2) ? acc2 : acc3;
      float s0 = __shfl(a, 0), s1 = __shfl(a, 16);
      float s2 = __shfl(a, 32), s3 = __shfl(a, 48);
      if (lane == j) { gi = s0; gf = s1; gg = s2; go = s3; }
    }

    if (lane < 4) {
      float xt = x_lds[t];
      gi += fmaf(xt, wih_g[0], bs_g[0]);
      gf += fmaf(xt, wih_g[1], bs_g[1]);
      gg += fmaf(xt, wih_g[2], bs_g[2]);
      go += fmaf(xt, wih_g[3], bs_g[3]);
      c_state  = sigf(gf) * c_state + sigf(gi) * tanh_fast(gg);
      float hn = sigf(go) * tanh_fast(c_state);
      llc_store1f(vbuf + (t & (NBUF - 1)) * HD + ubase + (lane & 3), hn);
    }
    vm_drain();                   // this wave's h-stores ACKED at MALL
    __syncthreads();              // => all 16 of this block's stores ACKED
    if (tid == 0)
      llc_store1u(done + cb, (unsigned)(t + 1));   // fire & forget

    // fused output projection for step t-1 (register-only, off crit path)
    if (doproj) {
      float p = 0.f;
#pragma unroll
      for (int m = 0; m < 4; ++m) { FMA4(p, hp4[m], wfc4[m]); }
#pragma unroll
      for (int s = 1; s < 64; s <<= 1) p += __shfl_xor(p, s);
      if (lane == 0) out[t - 1] = p + bfc_val;
    }
  }

  // ---- epilogue: out[TT-1] by block 0 -----------------------------------
  if (cb == 0) {
    for (;;) {
      unsigned v = llc_load1(done + lane);
      if (__all((int)v >= TT)) break;
    }
    f32x4 hv = llc_load4f(vbuf + ((TT - 1) & (NBUF - 1)) * HD + tid * 4);
    ((f32x4*)h_lds)[tid] = hv;
    __syncthreads();
    if (wave == 1) {
      float p = 0.f;
#pragma unroll
      for (int m = 0; m < 4; ++m) {
        float4 hm = *((const float4*)(h_lds + m * 256 + lane * 4));
        FMA4(p, hm, wfc4[m]);
      }
#pragma unroll
      for (int s = 1; s < 64; s <<= 1) p += __shfl_xor(p, s);
      if (lane == 0) out[TT - 1] = p + bfc_val;
    }
  }
}

extern "C" void kernel_launch(void* const* d_in, const int* in_sizes, int n_in,
                              void* d_out, int out_size, void* d_ws, size_t ws_size,
                              hipStream_t stream) {
  const float* x   = (const float*)d_in[0];
  const float* Wih = (const float*)d_in[1];
  const float* Whh = (const float*)d_in[2];
  const float* bih = (const float*)d_in[3];
  const float* bhh = (const float*)d_in[4];
  const float* Wfc = (const float*)d_in[5];
  const float* bfc = (const float*)d_in[6];
  float* out = (float*)d_out;

  // ws layout: [done: 64 u32 (pad to 512 B)][vbuf: NBUF*HD floats = 16 KB]
  unsigned* done = (unsigned*)d_ws;
  float*    vbuf = (float*)((char*)d_ws + 512);

  // zero done (0 < any t); vbuf is always written before read
  hipMemsetAsync(d_ws, 0, 512, stream);
  hipLaunchKernelGGL(lstm_persistent, dim3(NCB), dim3(NTHR), 0, stream,
                     x, Wih, Whh, bih, bhh, Wfc, bfc, out, done, vbuf);
}

// Round 8
// 40601.212 us; speedup vs baseline: 1.7677x; 1.0502x over previous
//
#include <hip/hip_runtime.h>

#define TT    8192
#define HD    1024
#define NBLK  256
#define NTHR  256
#define NBUF  4         // pair-ring depth — safety proof in comment below

typedef int i32x4 __attribute__((ext_vector_type(4)));
typedef int i32x2 __attribute__((ext_vector_type(2)));

// ---- LLC-coherent accesses (sc0 sc1 = bypass L1+L2, coherent at MALL) ----
__device__ __forceinline__ void llc_load_pair(const unsigned* p, i32x4& a, i32x4& b) {
  asm volatile("global_load_dwordx4 %0, %2, off sc0 sc1\n\t"
               "global_load_dwordx4 %1, %3, off sc0 sc1\n\t"
               "s_waitcnt vmcnt(0)"
               : "=&v"(a), "=&v"(b)
               : "v"(p), "v"(p + 4)
               : "memory");
}
__device__ __forceinline__ i32x4 llc_load4i(const int* p) {
  i32x4 r;
  asm volatile("global_load_dwordx4 %0, %1, off sc0 sc1\n\ts_waitcnt vmcnt(0)"
               : "=v"(r) : "v"(p) : "memory");
  return r;
}
__device__ __forceinline__ void llc_store2(unsigned* p, unsigned lo, unsigned hi) {
  i32x2 v; v.x = (int)lo; v.y = (int)hi;
  asm volatile("global_store_dwordx2 %0, %1, off sc0 sc1"
               :: "v"(p), "v"(v) : "memory");
}
__device__ __forceinline__ void llc_store1i(int* p, int v) {
  asm volatile("global_store_dword %0, %1, off sc0 sc1"
               :: "v"(p), "v"(v) : "memory");
}

__device__ __forceinline__ float sigf(float z) {
  return 1.0f / (1.0f + __expf(-z));
}
__device__ __forceinline__ float tanh_fast(float z) {
  float az = fabsf(z);
  float e  = __expf(2.0f * az);          // >= 1
  float t  = 1.0f - 2.0f / (e + 1.0f);
  return z < 0.0f ? -t : t;
}

#define FMA4(acc, hvv, wvv)                                      \
  acc = fmaf((hvv).x, (wvv).x, acc);                             \
  acc = fmaf((hvv).y, (wvv).y, acc);                             \
  acc = fmaf((hvv).z, (wvv).z, acc);                             \
  acc = fmaf((hvv).w, (wvv).w, acc);

// hbuf: unsigned[NBUF][HD][2] {value_bits, tag}; h of step t -> ring t%NBUF,
// tag t+1.  done: int[NBLK]; done[cb]=t+1 is a CONGESTION GATE (hint), not a
// correctness token — consumers tag-verify every pair they read.
//
// RING SAFETY (NBUF=4, hint gate): producer P overwrites buffer (t-1)%4 at
// step t+3 only after P's gate saw done[*] >= t+3.  done[Q]=t+3 is stored
// after Q's staging barrier of step t+2, which follows ALL of Q's verified
// reads for step t+2; Q reaching step t+2 means Q finished step t, i.e. Q's
// verified read of buffer (t-1)%4 completed.  So every block's step-t read
// of that buffer is complete before any overwrite.  Consumers spinning on
// tag==t therefore can never see the slot skip past t.  QED.
extern "C" __global__ __launch_bounds__(NTHR, 1)
void lstm_persistent(const float* __restrict__ x,
                     const float* __restrict__ W_ih,
                     const float* __restrict__ W_hh,
                     const float* __restrict__ b_ih,
                     const float* __restrict__ b_hh,
                     const float* __restrict__ W_fc,
                     const float* __restrict__ b_fc,
                     float* __restrict__ out,
                     int*      __restrict__ done,
                     unsigned* __restrict__ hbuf)
{
  __shared__ float x_lds[TT];     // 32 KB: whole input sequence
  __shared__ float h_lds[HD];     //  4 KB: broadcast of h_{t-1}

  const int tid  = threadIdx.x;
  const int wave = tid >> 6;
  const int lane = tid & 63;
  const int g    = lane >> 4;     // gate 0..3 (i,f,g,o)
  const int kc   = lane & 15;     // k-chunk within the 1024-dot
  const int cb   = blockIdx.x;
  const int unit = cb * 4 + wave; // this wave's hidden unit

  // ---- one-time staging -------------------------------------------------
  for (int i = tid; i < TT / 4; i += NTHR)
    ((float4*)x_lds)[i] = ((const float4*)x)[i];

  // W_hh row (gate g, unit) — lane covers k = m*64 + kc*4 + {0..3}
  float4 w4[16];
  {
    const float* wr = W_hh + (size_t)(g * HD + unit) * HD + kc * 4;
#pragma unroll
    for (int m = 0; m < 16; ++m)
      w4[m] = *((const float4*)(wr + m * 64));
  }
  float4 wfc4[4];
#pragma unroll
  for (int m = 0; m < 4; ++m)
    wfc4[m] = *((const float4*)(W_fc + m * 256 + lane * 4));
  const float bfc_val = b_fc[0];

  float wih_g[4], bs_g[4];
#pragma unroll
  for (int q = 0; q < 4; ++q) {
    int r = q * HD + unit;
    wih_g[q] = W_ih[r];
    bs_g[q]  = b_ih[r] + b_hh[r];
  }
  float c_state = 0.0f;
  __syncthreads();                // x_lds ready

  // gate-poll address: block-rotated so the 16 lines are hit in different
  // order by different blocks (spreads MALL bank pressure)
  const int* done_mine = done + (((lane + cb) & 63) << 2);

  // ---- the sequential scan ---------------------------------------------
  for (int t = 0; t < TT; ++t) {
    const bool doproj = (t > 0) && (wave == 1) && (cb == (t & 255));
    float accs = 0.0f;
    float4 hp4[4];

    if (t > 0) {
      // 1) congestion gate: wave 0 reads the whole done array (1 KB, 16
      //    lines) with one dwordx4 per lane until all 256 entries >= t
      if (wave == 0) {
        for (;;) {
          i32x4 d = llc_load4i(done_mine);
          if (__all(d.x >= t && d.y >= t && d.z >= t && d.w >= t)) break;
        }
      }
      __syncthreads();
      // 2) verified data read: own 4 tagged pairs (32 B); ~1 iteration
      const unsigned* src = hbuf + (((t - 1) & (NBUF - 1)) * HD + tid * 4) * 2;
      i32x4 A, B;
      do {
        llc_load_pair(src, A, B);
      } while (!(A.y == t && A.w == t && B.y == t && B.w == t));
      float4 hv;
      hv.x = __int_as_float(A.x); hv.y = __int_as_float(A.z);
      hv.z = __int_as_float(B.x); hv.w = __int_as_float(B.z);
      ((float4*)h_lds)[tid] = hv;
      __syncthreads();            // staging barrier (also orders done-store)

      // fragments + 64 FMAs (4 independent sub-chains)
      const float* hp = h_lds + kc * 4;
      float s0 = 0.f, s1 = 0.f, s2 = 0.f, s3 = 0.f;
#pragma unroll
      for (int mb = 0; mb < 4; ++mb) {
        float4 ha = *((const float4*)(hp + (mb * 4 + 0) * 64));
        float4 hb = *((const float4*)(hp + (mb * 4 + 1) * 64));
        float4 hc = *((const float4*)(hp + (mb * 4 + 2) * 64));
        float4 hd = *((const float4*)(hp + (mb * 4 + 3) * 64));
        FMA4(s0, ha, w4[mb * 4 + 0]);
        FMA4(s1, hb, w4[mb * 4 + 1]);
        FMA4(s2, hc, w4[mb * 4 + 2]);
        FMA4(s3, hd, w4[mb * 4 + 3]);
      }
      accs = (s0 + s1) + (s2 + s3);

      if (doproj) {
#pragma unroll
        for (int m = 0; m < 4; ++m)
          hp4[m] = *((const float4*)(h_lds + m * 256 + lane * 4));
      }
    }

    // 4-round butterfly over kc: every lane in a gate-group gets the row sum
#pragma unroll
    for (int s = 1; s < 16; s <<= 1)
      accs += __shfl_xor(accs, s);

    float gi = __shfl(accs, 0);
    float gf = __shfl(accs, 16);
    float gg = __shfl(accs, 32);
    float go = __shfl(accs, 48);

    if (lane == 0) {
      float xt = x_lds[t];
      gi += fmaf(xt, wih_g[0], bs_g[0]);
      gf += fmaf(xt, wih_g[1], bs_g[1]);
      gg += fmaf(xt, wih_g[2], bs_g[2]);
      go += fmaf(xt, wih_g[3], bs_g[3]);
      c_state  = sigf(gf) * c_state + sigf(gi) * tanh_fast(gg);
      float hn = sigf(go) * tanh_fast(c_state);
      llc_store2(hbuf + (((t & (NBUF - 1)) * HD + unit) * 2),
                 __float_as_uint(hn), (unsigned)(t + 1));  // fire & forget
    }
    // gate hint: no drain needed — tags certify the data; this only stems
    // the poll flood.  Stored by tid 0 right after its wave's pair store.
    if (tid == 0)
      llc_store1i(done + cb, t + 1);

    // fused output projection for step t-1 (register-only, off crit path)
    if (doproj) {
      float p = 0.f;
#pragma unroll
      for (int m = 0; m < 4; ++m) { FMA4(p, hp4[m], wfc4[m]); }
#pragma unroll
      for (int s = 1; s < 64; s <<= 1) p += __shfl_xor(p, s);
      if (lane == 0) out[t - 1] = p + bfc_val;
    }
  }

  // ---- epilogue: out[TT-1] by block 0 (direct verified read) ------------
  if (cb == 0) {
    const unsigned* src = hbuf + (((TT - 1) & (NBUF - 1)) * HD + tid * 4) * 2;
    i32x4 A, B;
    do {
      llc_load_pair(src, A, B);
    } while (!(A.y == TT && A.w == TT && B.y == TT && B.w == TT));
    float4 hv;
    hv.x = __int_as_float(A.x); hv.y = __int_as_float(A.z);
    hv.z = __int_as_float(B.x); hv.w = __int_as_float(B.z);
    ((float4*)h_lds)[tid] = hv;
    __syncthreads();
    if (wave == 1) {
      float p = 0.f;
#pragma unroll
      for (int m = 0; m < 4; ++m) {
        float4 hm = *((const float4*)(h_lds + m * 256 + lane * 4));
        FMA4(p, hm, wfc4[m]);
      }
#pragma unroll
      for (int s = 1; s < 64; s <<= 1) p += __shfl_xor(p, s);
      if (lane == 0) out[TT - 1] = p + bfc_val;
    }
  }
}

extern "C" void kernel_launch(void* const* d_in, const int* in_sizes, int n_in,
                              void* d_out, int out_size, void* d_ws, size_t ws_size,
                              hipStream_t stream) {
  const float* x   = (const float*)d_in[0];
  const float* Wih = (const float*)d_in[1];
  const float* Whh = (const float*)d_in[2];
  const float* bih = (const float*)d_in[3];
  const float* bhh = (const float*)d_in[4];
  const float* Wfc = (const float*)d_in[5];
  const float* bfc = (const float*)d_in[6];
  float* out = (float*)d_out;

  // ws layout: [done: NBLK int = 1 KB][hbuf: NBUF*HD tagged pairs = 32 KB]
  int*      done = (int*)d_ws;
  unsigned* hbuf = (unsigned*)((char*)d_ws + NBLK * sizeof(int));
  size_t init_bytes = NBLK * sizeof(int) + NBUF * HD * 2 * sizeof(unsigned);

  // zeros: tag 0 never equals any expected tag (>=1); done 0 < any t
  hipMemsetAsync(d_ws, 0, init_bytes, stream);
  hipLaunchKernelGGL(lstm_persistent, dim3(NBLK), dim3(NTHR), 0, stream,
                     x, Wih, Whh, bih, bhh, Wfc, bfc, out, done, hbuf);
}

// Round 9
// 23678.825 us; speedup vs baseline: 3.0310x; 1.7147x over previous
//
#include <hip/hip_runtime.h>

#define TT    8192
#define HD    1024
#define NBLK  256       // compute blocks; block NBLK is the dedicated sequencer
#define NTHR  256
#define NBUF  4         // pair-ring depth — safety proof below
#define NREP  8         // flag replicas, one 64B line each

typedef int i32x4 __attribute__((ext_vector_type(4)));
typedef int i32x2 __attribute__((ext_vector_type(2)));

// ---- LLC-coherent accesses (sc0 sc1 = bypass L1+L2, coherent at MALL) ----
__device__ __forceinline__ void llc_load_pair(const unsigned* p, i32x4& a, i32x4& b) {
  asm volatile("global_load_dwordx4 %0, %2, off sc0 sc1\n\t"
               "global_load_dwordx4 %1, %3, off sc0 sc1\n\t"
               "s_waitcnt vmcnt(0)"
               : "=&v"(a), "=&v"(b)
               : "v"(p), "v"(p + 4)
               : "memory");
}
__device__ __forceinline__ unsigned llc_load1(const unsigned* p) {
  unsigned r;
  asm volatile("global_load_dword %0, %1, off sc0 sc1\n\ts_waitcnt vmcnt(0)"
               : "=v"(r) : "v"(p) : "memory");
  return r;
}
__device__ __forceinline__ void llc_store2(unsigned* p, unsigned lo, unsigned hi) {
  i32x2 v; v.x = (int)lo; v.y = (int)hi;
  asm volatile("global_store_dwordx2 %0, %1, off sc0 sc1"
               :: "v"(p), "v"(v) : "memory");
}
__device__ __forceinline__ void llc_store1(unsigned* p, unsigned v) {
  asm volatile("global_store_dword %0, %1, off sc0 sc1"
               :: "v"(p), "v"(v) : "memory");
}

__device__ __forceinline__ float sigf(float z) {
  return 1.0f / (1.0f + __expf(-z));
}
__device__ __forceinline__ float tanh_fast(float z) {
  float az = fabsf(z);
  float e  = __expf(2.0f * az);          // >= 1
  float t  = 1.0f - 2.0f / (e + 1.0f);
  return z < 0.0f ? -t : t;
}

#define FMA4(acc, hvv, wvv)                                      \
  acc = fmaf((hvv).x, (wvv).x, acc);                             \
  acc = fmaf((hvv).y, (wvv).y, acc);                             \
  acc = fmaf((hvv).z, (wvv).z, acc);                             \
  acc = fmaf((hvv).w, (wvv).w, acc);

// hbuf: unsigned[NBUF][HD][2] {value_bits, tag}; h of step t -> ring t%NBUF,
// tag t+1 (single 8-B store: tag certifies value).
// flag[r*16]: replicas; flag >= t  <=>  the SEQUENCER verified all 1024 tags
// of step t-1 at the MALL.  Consumers therefore read pairs WITHOUT verifying.
//
// RING SAFETY (NBUF=4): producer P overwrites slot (t-1)%4 at step t+3 only
// after its gate saw flag >= t+3.  The sequencer raises flag t+3 only after
// every block stored h_{t+2}; a block stores h_{t+2} only after reading
// h_{t+1}, which required flag >= t+2, which required every block to have
// stored h_{t+1}, which required reading h_t from slot (t-1)%4.  Hence all
// step-t reads of that slot are complete before any overwrite.  QED.
extern "C" __global__ __launch_bounds__(NTHR, 1)
void lstm_persistent(const float* __restrict__ x,
                     const float* __restrict__ W_ih,
                     const float* __restrict__ W_hh,
                     const float* __restrict__ b_ih,
                     const float* __restrict__ b_hh,
                     const float* __restrict__ W_fc,
                     const float* __restrict__ b_fc,
                     float* __restrict__ out,
                     unsigned* __restrict__ flag,
                     unsigned* __restrict__ hbuf)
{
  const int tid = threadIdx.x;
  const int blk = blockIdx.x;

  // ================= block NBLK: dedicated sequencer =====================
  // Polls tag words during the producers' store window; raises the flag one
  // detect-latency after the LAST store of each step (no compute in between).
  if (blk == NBLK) {
    for (int t = 0; t < TT; ++t) {
      const unsigned* src = hbuf + (((t & (NBUF - 1)) * HD + tid * 4) * 2);
      i32x4 A, B;
      const int want = t + 1;
      do {
        llc_load_pair(src, A, B);
      } while (!(A.y == want && A.w == want && B.y == want && B.w == want));
      __syncthreads();                    // all 1024 tags verified
      if (tid < NREP)
        llc_store1(flag + (tid << 4), (unsigned)want);
    }
    return;
  }

  // ================= blocks 0..255: compute ==============================
  __shared__ float x_lds[TT];     // 32 KB: whole input sequence
  __shared__ float h_lds[HD];     //  4 KB: broadcast of h_{t-1}

  const int wave = tid >> 6;
  const int lane = tid & 63;
  const int g    = lane >> 4;     // gate 0..3 (i,f,g,o)
  const int kc   = lane & 15;     // k-chunk within the 1024-dot
  const int unit = blk * 4 + wave;

  // ---- one-time staging -------------------------------------------------
  for (int i = tid; i < TT / 4; i += NTHR)
    ((float4*)x_lds)[i] = ((const float4*)x)[i];

  // W_hh row (gate g, unit) — lane covers k = m*64 + kc*4 + {0..3}
  float4 w4[16];
  {
    const float* wr = W_hh + (size_t)(g * HD + unit) * HD + kc * 4;
#pragma unroll
    for (int m = 0; m < 16; ++m)
      w4[m] = *((const float4*)(wr + m * 64));
  }
  float4 wfc4[4];
#pragma unroll
  for (int m = 0; m < 4; ++m)
    wfc4[m] = *((const float4*)(W_fc + m * 256 + lane * 4));
  const float bfc_val = b_fc[0];

  float wih_g[4], bs_g[4];
#pragma unroll
  for (int q = 0; q < 4; ++q) {
    int r = q * HD + unit;
    wih_g[q] = W_ih[r];
    bs_g[q]  = b_ih[r] + b_hh[r];
  }
  float c_state = 0.0f;
  __syncthreads();                // x_lds ready

  const unsigned* flag_mine = flag + ((blk & (NREP - 1)) << 4);

  // ---- the sequential scan ---------------------------------------------
  for (int t = 0; t < TT; ++t) {
    const bool doproj = (t > 0) && (wave == 1) && (blk == (t & 255));
    float accs = 0.0f;
    float4 hp4[4];

    if (t > 0) {
      // gate: replica flag (1 coalesced same-address tx per wave per round)
      while (llc_load1(flag_mine) < (unsigned)t) { }
      // certified single-shot read: flag guarantees tags==t, no verify loop
      const unsigned* src = hbuf + (((t - 1) & (NBUF - 1)) * HD + tid * 4) * 2;
      i32x4 A, B;
      llc_load_pair(src, A, B);
      float4 hv;
      hv.x = __int_as_float(A.x); hv.y = __int_as_float(A.z);
      hv.z = __int_as_float(B.x); hv.w = __int_as_float(B.z);
      ((float4*)h_lds)[tid] = hv;
      __syncthreads();

      // fragments + 64 FMAs (4 independent sub-chains)
      const float* hp = h_lds + kc * 4;
      float s0 = 0.f, s1 = 0.f, s2 = 0.f, s3 = 0.f;
#pragma unroll
      for (int mb = 0; mb < 4; ++mb) {
        float4 ha = *((const float4*)(hp + (mb * 4 + 0) * 64));
        float4 hb = *((const float4*)(hp + (mb * 4 + 1) * 64));
        float4 hc = *((const float4*)(hp + (mb * 4 + 2) * 64));
        float4 hd = *((const float4*)(hp + (mb * 4 + 3) * 64));
        FMA4(s0, ha, w4[mb * 4 + 0]);
        FMA4(s1, hb, w4[mb * 4 + 1]);
        FMA4(s2, hc, w4[mb * 4 + 2]);
        FMA4(s3, hd, w4[mb * 4 + 3]);
      }
      accs = (s0 + s1) + (s2 + s3);

      if (doproj) {
#pragma unroll
        for (int m = 0; m < 4; ++m)
          hp4[m] = *((const float4*)(h_lds + m * 256 + lane * 4));
      }
    }

    // 4-round butterfly over kc: every lane in a gate-group gets the row sum
#pragma unroll
    for (int s = 1; s < 16; s <<= 1)
      accs += __shfl_xor(accs, s);

    float gi = __shfl(accs, 0);
    float gf = __shfl(accs, 16);
    float gg = __shfl(accs, 32);
    float go = __shfl(accs, 48);

    if (lane == 0) {
      float xt = x_lds[t];
      gi += fmaf(xt, wih_g[0], bs_g[0]);
      gf += fmaf(xt, wih_g[1], bs_g[1]);
      gg += fmaf(xt, wih_g[2], bs_g[2]);
      go += fmaf(xt, wih_g[3], bs_g[3]);
      c_state  = sigf(gf) * c_state + sigf(gi) * tanh_fast(gg);
      float hn = sigf(go) * tanh_fast(c_state);
      llc_store2(hbuf + (((t & (NBUF - 1)) * HD + unit) * 2),
                 __float_as_uint(hn), (unsigned)(t + 1));  // fire & forget
    }

    // fused output projection for step t-1 (register-only, off crit path)
    if (doproj) {
      float p = 0.f;
#pragma unroll
      for (int m = 0; m < 4; ++m) { FMA4(p, hp4[m], wfc4[m]); }
#pragma unroll
      for (int s = 1; s < 64; s <<= 1) p += __shfl_xor(p, s);
      if (lane == 0) out[t - 1] = p + bfc_val;
    }
  }

  // ---- epilogue: out[TT-1] by block 0 (tag-verified direct read) ---------
  if (blk == 0) {
    const unsigned* src = hbuf + (((TT - 1) & (NBUF - 1)) * HD + tid * 4) * 2;
    i32x4 A, B;
    do {
      llc_load_pair(src, A, B);
    } while (!(A.y == TT && A.w == TT && B.y == TT && B.w == TT));
    float4 hv;
    hv.x = __int_as_float(A.x); hv.y = __int_as_float(A.z);
    hv.z = __int_as_float(B.x); hv.w = __int_as_float(B.z);
    ((float4*)h_lds)[tid] = hv;
    __syncthreads();
    if (wave == 1) {
      float p = 0.f;
#pragma unroll
      for (int m = 0; m < 4; ++m) {
        float4 hm = *((const float4*)(h_lds + m * 256 + lane * 4));
        FMA4(p, hm, wfc4[m]);
      }
#pragma unroll
      for (int s = 1; s < 64; s <<= 1) p += __shfl_xor(p, s);
      if (lane == 0) out[TT - 1] = p + bfc_val;
    }
  }
}

extern "C" void kernel_launch(void* const* d_in, const int* in_sizes, int n_in,
                              void* d_out, int out_size, void* d_ws, size_t ws_size,
                              hipStream_t stream) {
  const float* x   = (const float*)d_in[0];
  const float* Wih = (const float*)d_in[1];
  const float* Whh = (const float*)d_in[2];
  const float* bih = (const float*)d_in[3];
  const float* bhh = (const float*)d_in[4];
  const float* Wfc = (const float*)d_in[5];
  const float* bfc = (const float*)d_in[6];
  float* out = (float*)d_out;

  // ws layout: [flag: NREP lines of 64 B][hbuf: NBUF*HD tagged pairs = 32 KB]
  unsigned* flag = (unsigned*)d_ws;
  unsigned* hbuf = flag + NREP * 16;
  size_t init_bytes = (NREP * 16 + NBUF * HD * 2) * sizeof(unsigned);

  // zeros: tag 0 never equals any expected tag (>=1); flag 0 < any t
  hipMemsetAsync(d_ws, 0, init_bytes, stream);
  hipLaunchKernelGGL(lstm_persistent, dim3(NBLK + 1), dim3(NTHR), 0, stream,
                     x, Wih, Whh, bih, bhh, Wfc, bfc, out, flag, hbuf);
}